// Round 16
// baseline (361.807 us; speedup 1.0000x reference)
//
#include <hip/hip_runtime.h>
#include <hip/hip_bf16.h>

// y = x @ (W^T * S), S = sum_{k=0}^{100} (-M)^k ~= prod_{i=0}^{3} (I + A^(2^i)), A = -M.
// Chain: 4 k-parallel launches; last writes P k-major bf16 Ptk[kt][col][32] (verified R7-R14).
// GEMM: R12's pipeline at HALF serial depth (split-K x2). Block = 2 waves over one 64x128
// tile; wave q owns k in [256q, 256q+256) -> 8 vmcnt-gated steps instead of 16. Partials
// merged at the end via the dead A-ring LDS. R15 RACE FIX: s_barrier BEFORE the partial
// writes (the exchange buffer aliases the partner's A-ring; without the barrier a fast
// wave clobbers tiles the partner is still reading).

typedef float f32x4 __attribute__((ext_vector_type(4)));
typedef __bf16 bf16x8 __attribute__((ext_vector_type(8)));

#define IN 512
#define OUT 256
#define BATCH 65536

#define GLOAD_LDS16(gp, lp)                                                              \
    __builtin_amdgcn_global_load_lds((const __attribute__((address_space(1))) void*)(gp), \
                                     (__attribute__((address_space(3))) void*)(lp), 16, 0, 0)

// ---------------- chain: k-parallel small matmuls (verified rounds 1-14) ----------------
__device__ __forceinline__ void chain_core(const float (*sA)[256], const float* __restrict__ B,
                                           int j, int q, float acc[8]) {
#pragma unroll
    for (int r = 0; r < 8; ++r) acc[r] = 0.f;
    const int kbase = q * 64;
#pragma unroll
    for (int it = 0; it < 16; ++it) {
        const int k = kbase + it * 4;
        const float b0 = B[(k + 0) * 256 + j];
        const float b1 = B[(k + 1) * 256 + j];
        const float b2 = B[(k + 2) * 256 + j];
        const float b3 = B[(k + 3) * 256 + j];
#pragma unroll
        for (int r = 0; r < 8; ++r) {
            const f32x4 av = *(const f32x4*)&sA[r][k];
            acc[r] += av[0] * b0 + av[1] * b1 + av[2] * b2 + av[3] * b3;
        }
    }
}

__global__ __launch_bounds__(1024) void nsm_chain_step(const float* __restrict__ Bmat,
                                                       const float* __restrict__ Pin,
                                                       float* __restrict__ Tout,
                                                       float* __restrict__ Pout,
                                                       const int first) {
    __shared__ float sA[8][256];
    __shared__ float ws[4][8][256];
    const int t = threadIdx.x, j = t & 255, q = t >> 8, b = blockIdx.x;
    float acc[8];
    const bool isT = (b < 32);
    if (isT) {
        const int i0 = b * 8;
        sA[2 * q][j]     = Bmat[(i0 + 2 * q) * 256 + j];
        sA[2 * q + 1][j] = Bmat[(i0 + 2 * q + 1) * 256 + j];
    } else {
        const int i0 = (b - 32) * 8;
        if (first) {
            sA[2 * q][j]     = Pin[j * IN + i0 + 2 * q];
            sA[2 * q + 1][j] = Pin[j * IN + i0 + 2 * q + 1];
        } else {
            sA[2 * q][j]     = Pin[(i0 + 2 * q) * 256 + j];
            sA[2 * q + 1][j] = Pin[(i0 + 2 * q + 1) * 256 + j];
        }
    }
    __syncthreads();
    chain_core(sA, Bmat, j, q, acc);
#pragma unroll
    for (int r = 0; r < 8; ++r) ws[q][r][j] = acc[r];
    __syncthreads();
#pragma unroll
    for (int d = 0; d < 2; ++d) {
        const int r = 2 * q + d;
        const float v = ws[0][r][j] + ws[1][r][j] + ws[2][r][j] + ws[3][r][j];
        if (isT) {
            const int i0 = b * 8;
            Tout[(i0 + r) * 256 + j] = v;
        } else {
            const int i0 = (b - 32) * 8;
            Pout[(i0 + r) * 256 + j] = first ? (sA[r][j] - v) : (sA[r][j] + v);
        }
    }
}

// grid 64: P_final = Pin + Pin*Bmat, written K-MAJOR bf16: Ptk[kt][col][kk] (verified R7-R14).
__global__ __launch_bounds__(1024) void nsm_chain_last(const float* __restrict__ Bmat,
                                                       const float* __restrict__ Pin,
                                                       __bf16* __restrict__ Ptk) {
    __shared__ float sA[8][256];
    __shared__ float ws[4][8][256];
    const int t = threadIdx.x, j = t & 255, q = t >> 8, b = blockIdx.x;
    const int i0 = b * 8;  // k-range [i0, i0+8)
    float acc[8];
    sA[2 * q][j]     = Pin[(i0 + 2 * q) * 256 + j];
    sA[2 * q + 1][j] = Pin[(i0 + 2 * q + 1) * 256 + j];
    __syncthreads();
    chain_core(sA, Bmat, j, q, acc);
#pragma unroll
    for (int r = 0; r < 8; ++r) ws[q][r][j] = acc[r];
    __syncthreads();
#pragma unroll
    for (int d = 0; d < 2; ++d) {
        const int r = 2 * q + d;
        const float v = ws[0][r][j] + ws[1][r][j] + ws[2][r][j] + ws[3][r][j];
        sA[r][j] += v;
    }
    __syncthreads();
    const int c = t >> 2, sub = t & 3;
    union { __bf16 h[2]; unsigned u; } pk;
    pk.h[0] = (__bf16)sA[sub * 2][c];
    pk.h[1] = (__bf16)sA[sub * 2 + 1][c];
    *(unsigned*)((void*)&Ptk[(size_t)(i0 >> 5) * 8192 + c * 32 + (i0 & 31) + sub * 2]) = pk.u;
}

// ---------------- big GEMM: y[65536][256] = x[65536][512] @ P ----------------
// Grid 2048 x 128 thr (2 waves, split-K). bid -> (xcd = bid&7, w = bid>>3); the two
// n-halves of an x-stripe are adjacent on the SAME XCD. Block output 64x128; wave q
// accumulates k in [256q, 256q+256) = 8 tiles of 32. A: per-wave private LDS ring-2
// xs[q][2][64][32] (32 KB total), 8 gload_lds/tile. B: 8 pinned asm loads/tile into
// alternating reg sets. Steady vmcnt(16). Two end barriers: (1) both waves done with
// their A-rings, (2) partials visible.
__global__ __launch_bounds__(128, 2) void nsm_gemm_xP(const float* __restrict__ x,
                                                      const __bf16* __restrict__ Ptk,
                                                      float* __restrict__ y) {
    __shared__ float xs[2][2][64][32];  // [wave][ring][row][k] 32 KB; reused for exchange
    const int tid = threadIdx.x;
    const int q = tid >> 6, lane = tid & 63;
    const int l15 = lane & 15, lhi = lane >> 4;

    const unsigned bid = blockIdx.x;
    const int xcd = bid & 7;
    const int w = bid >> 3;                    // 0..255
    const int stripe = xcd * 128 + (w >> 1);   // 0..1023
    const int nh = w & 1;
    const int m0 = stripe * 64;
    const int n0 = nh * 128;

    auto stageA = [&](int buf, int s) {
        const int kk = (q * 8 + s) * 32;
#pragma unroll
        for (int i = 0; i < 8; ++i) {
            const int r0 = i * 8;
            const int row = r0 + (lane >> 3);
            const int gch = (lane & 7) ^ (row & 7);
            GLOAD_LDS16(x + (size_t)(m0 + row) * IN + kk + gch * 4, &xs[q][buf][r0][0]);
        }
    };

    // B: col = n0 + nt*16 + l15 (64 B/col), k-chunk lhi*16 B; tile stride 16 KB.
    unsigned long long baddr = (unsigned long long)(const void*)Ptk +
                               (unsigned long long)(n0 * 64 + l15 * 64 + lhi * 16 + q * 131072);
    bf16x8 b0[8], b1[8];

#define LOADB(SET)                                                                        \
    do {                                                                                  \
        const unsigned long long baddr2 = baddr + 4096;                                   \
        _Pragma("unroll")                                                                 \
        for (int nt = 0; nt < 8; ++nt)                                                    \
            asm volatile("global_load_dwordx4 %0, %1, off offset:%2"                      \
                         : "=v"(SET[nt])                                                  \
                         : "v"(nt < 4 ? baddr : baddr2), "n"((nt & 3) * 1024));           \
        baddr += 16384;                                                                   \
    } while (0)

    f32x4 acc[4][8];
#pragma unroll
    for (int a = 0; a < 4; ++a)
#pragma unroll
        for (int c = 0; c < 8; ++c) acc[a][c] = (f32x4){0.f, 0.f, 0.f, 0.f};

    stageA(0, 0);
    LOADB(b0);
    stageA(1, 1);
    LOADB(b1);

#pragma unroll
    for (int s = 0; s < 8; ++s) {
        if (s < 7) {
            asm volatile("s_waitcnt vmcnt(16)" ::: "memory");  // tile s landed; s+1 in flight
        } else {
            asm volatile("s_waitcnt vmcnt(0)" ::: "memory");
        }
        __builtin_amdgcn_sched_barrier(0);

        const int buf = s & 1;  // static after full unroll
        f32x4 f0[4], f1[4];
#pragma unroll
        for (int mt = 0; mt < 4; ++mt) {
            const int row = mt * 16 + l15;
            const int c0 = (2 * lhi) ^ (row & 7);
            f0[mt] = *(const f32x4*)&xs[q][buf][row][c0 * 4];
            f1[mt] = *(const f32x4*)&xs[q][buf][row][(c0 ^ 1) * 4];
        }
        asm volatile("s_waitcnt lgkmcnt(0)" ::: "memory");  // frag reads in regs
        __builtin_amdgcn_sched_barrier(0);
        if (s < 6) stageA(buf, s + 2);  // ring-2 overwrite now safe

        bf16x8 af[4];
#pragma unroll
        for (int mt = 0; mt < 4; ++mt) {
            bf16x8 t;
            t[0] = (__bf16)f0[mt][0]; t[1] = (__bf16)f0[mt][1];
            t[2] = (__bf16)f0[mt][2]; t[3] = (__bf16)f0[mt][3];
            t[4] = (__bf16)f1[mt][0]; t[5] = (__bf16)f1[mt][1];
            t[6] = (__bf16)f1[mt][2]; t[7] = (__bf16)f1[mt][3];
            af[mt] = t;
        }

        if ((s & 1) == 0) {
#pragma unroll
            for (int mt = 0; mt < 4; ++mt)
#pragma unroll
                for (int nt = 0; nt < 8; ++nt)
                    acc[mt][nt] = __builtin_amdgcn_mfma_f32_16x16x32_bf16(af[mt], b0[nt], acc[mt][nt], 0, 0, 0);
            if (s < 6) LOADB(b0);
        } else {
#pragma unroll
            for (int mt = 0; mt < 4; ++mt)
#pragma unroll
                for (int nt = 0; nt < 8; ++nt)
                    acc[mt][nt] = __builtin_amdgcn_mfma_f32_16x16x32_bf16(af[mt], b1[nt], acc[mt][nt], 0, 0, 0);
            if (s < 6) LOADB(b1);
        }
    }
#undef LOADB

    // ---- R15 race fix: both waves must be DONE with their A-rings before the exchange
    // overwrites them (vmcnt(0)+lgkmcnt(0) already drained in the last iteration).
    __builtin_amdgcn_s_barrier();

    // split-K merge through the dead A-ring (32 KB = 2 halves x [128 col][32 row] f32).
    // Wave q sends rows [32(q^1), 32(q^1)+32) into half q^1, keeps rows [32q, 32q+32).
    float* eb = &xs[0][0][0][0];
    const int sh = q ^ 1;
#pragma unroll
    for (int ml = 0; ml < 2; ++ml) {
#pragma unroll
        for (int nt = 0; nt < 8; ++nt) {
            const int col = nt * 16 + l15;
            const int rowp = ml * 16 + lhi * 4;
            *(f32x4*)&eb[(((sh * 128 + col) * 32 + rowp) ^ ((col & 7) << 2))] = acc[sh * 2 + ml][nt];
        }
    }
    asm volatile("s_waitcnt lgkmcnt(0)" ::: "memory");
    __builtin_amdgcn_sched_barrier(0);
    __builtin_amdgcn_s_barrier();  // partner's partials visible
#pragma unroll
    for (int ml = 0; ml < 2; ++ml) {
#pragma unroll
        for (int nt = 0; nt < 8; ++nt) {
            const int col = nt * 16 + l15;
            const int rowp = ml * 16 + lhi * 4;
            const f32x4 v = *(const f32x4*)&eb[(((q * 128 + col) * 32 + rowp) ^ ((col & 7) << 2))];
            acc[q * 2 + ml][nt] += v;
        }
    }

#pragma unroll
    for (int ml = 0; ml < 2; ++ml) {
        const int mt = q * 2 + ml;
#pragma unroll
        for (int nt = 0; nt < 8; ++nt) {
            const int col = n0 + nt * 16 + l15;
            const int row = m0 + mt * 16 + lhi * 4;
#pragma unroll
            for (int r = 0; r < 4; ++r) y[(size_t)(row + r) * OUT + col] = acc[mt][nt][r];
        }
    }
}

extern "C" void kernel_launch(void* const* d_in, const int* in_sizes, int n_in,
                              void* d_out, int out_size, void* d_ws, size_t ws_size,
                              hipStream_t stream) {
    const float* x = (const float*)d_in[0];   // [65536][512]
    const float* W = (const float*)d_in[1];   // [256][512]
    const float* M = (const float*)d_in[2];   // [256][256]
    float* y = (float*)d_out;                 // [65536][256]

    char* ws = (char*)d_ws;
    float* Ta = (float*)(ws);                   // 256 KB
    float* Tb = (float*)(ws + (256 << 10));     // 256 KB
    float* Pa = (float*)(ws + (512 << 10));     // 512 KB
    float* Pb = (float*)(ws + (1024 << 10));    // 512 KB
    __bf16* Ptk = (__bf16*)(ws + (1536 << 10)); // 256 KB  bf16 k-major [16][256][32]

    // chain: P = W^T * prod_{i=0..3} (I + A^(2^i)), A = -M  (sum_{k=0}^{15} A^k)
    nsm_chain_step<<<96, 1024, 0, stream>>>(M, W, Ta, Pa, 1);   // Ta=A^2, Pa=P0=W^T(I+A)
    nsm_chain_step<<<96, 1024, 0, stream>>>(Ta, Pa, Tb, Pb, 0); // Tb=A^4, Pb=P1=P0(I+A^2)
    nsm_chain_step<<<96, 1024, 0, stream>>>(Tb, Pb, Ta, Pa, 0); // Ta=A^8, Pa=P2=P1(I+A^4)
    nsm_chain_last<<<64, 1024, 0, stream>>>(Ta, Pa, Ptk);       // Ptk = bf16((P2(I+A^8))^T)
    nsm_gemm_xP<<<2048, 128, 0, stream>>>(x, Ptk, y);           // y = x @ P
}

// Round 17
// 70.022 us; speedup vs baseline: 5.1670x; 5.1670x over previous
//
#include <hip/hip_runtime.h>
#include <hip/hip_bf16.h>

// y = x @ (W^T * S), S = sum_{k=0}^{100} (-M)^k ~= prod_{i=0}^{3} (I + A^(2^i)), A = -M.
// Chain: 4 k-parallel launches; last writes P k-major bf16 Ptk[kt][col][32] (verified R7-R14).
// GEMM: split-K x2 at half serial depth (8 vmcnt-gated steps/wave vs 16 -- the invariant
// shared by every ~60us round). R16 POST-MORTEM FIX: the split-K merge previously indexed
// acc[q^1 ...] with RUNTIME q -> whole accumulator demoted to scratch (VGPR=128, +84 MB
// spill traffic, 6x slowdown; guide rule #20). Now the merge/store is branched on
// wave-uniform q with LITERAL acc indices -- acc stays in registers.

typedef float f32x4 __attribute__((ext_vector_type(4)));
typedef __bf16 bf16x8 __attribute__((ext_vector_type(8)));

#define IN 512
#define OUT 256
#define BATCH 65536

#define GLOAD_LDS16(gp, lp)                                                              \
    __builtin_amdgcn_global_load_lds((const __attribute__((address_space(1))) void*)(gp), \
                                     (__attribute__((address_space(3))) void*)(lp), 16, 0, 0)

// ---------------- chain: k-parallel small matmuls (verified rounds 1-14) ----------------
__device__ __forceinline__ void chain_core(const float (*sA)[256], const float* __restrict__ B,
                                           int j, int q, float acc[8]) {
#pragma unroll
    for (int r = 0; r < 8; ++r) acc[r] = 0.f;
    const int kbase = q * 64;
#pragma unroll
    for (int it = 0; it < 16; ++it) {
        const int k = kbase + it * 4;
        const float b0 = B[(k + 0) * 256 + j];
        const float b1 = B[(k + 1) * 256 + j];
        const float b2 = B[(k + 2) * 256 + j];
        const float b3 = B[(k + 3) * 256 + j];
#pragma unroll
        for (int r = 0; r < 8; ++r) {
            const f32x4 av = *(const f32x4*)&sA[r][k];
            acc[r] += av[0] * b0 + av[1] * b1 + av[2] * b2 + av[3] * b3;
        }
    }
}

__global__ __launch_bounds__(1024) void nsm_chain_step(const float* __restrict__ Bmat,
                                                       const float* __restrict__ Pin,
                                                       float* __restrict__ Tout,
                                                       float* __restrict__ Pout,
                                                       const int first) {
    __shared__ float sA[8][256];
    __shared__ float ws[4][8][256];
    const int t = threadIdx.x, j = t & 255, q = t >> 8, b = blockIdx.x;
    float acc[8];
    const bool isT = (b < 32);
    if (isT) {
        const int i0 = b * 8;
        sA[2 * q][j]     = Bmat[(i0 + 2 * q) * 256 + j];
        sA[2 * q + 1][j] = Bmat[(i0 + 2 * q + 1) * 256 + j];
    } else {
        const int i0 = (b - 32) * 8;
        if (first) {
            sA[2 * q][j]     = Pin[j * IN + i0 + 2 * q];
            sA[2 * q + 1][j] = Pin[j * IN + i0 + 2 * q + 1];
        } else {
            sA[2 * q][j]     = Pin[(i0 + 2 * q) * 256 + j];
            sA[2 * q + 1][j] = Pin[(i0 + 2 * q + 1) * 256 + j];
        }
    }
    __syncthreads();
    chain_core(sA, Bmat, j, q, acc);
#pragma unroll
    for (int r = 0; r < 8; ++r) ws[q][r][j] = acc[r];
    __syncthreads();
#pragma unroll
    for (int d = 0; d < 2; ++d) {
        const int r = 2 * q + d;
        const float v = ws[0][r][j] + ws[1][r][j] + ws[2][r][j] + ws[3][r][j];
        if (isT) {
            const int i0 = b * 8;
            Tout[(i0 + r) * 256 + j] = v;
        } else {
            const int i0 = (b - 32) * 8;
            Pout[(i0 + r) * 256 + j] = first ? (sA[r][j] - v) : (sA[r][j] + v);
        }
    }
}

// grid 64: P_final = Pin + Pin*Bmat, written K-MAJOR bf16: Ptk[kt][col][kk] (verified R7-R14).
__global__ __launch_bounds__(1024) void nsm_chain_last(const float* __restrict__ Bmat,
                                                       const float* __restrict__ Pin,
                                                       __bf16* __restrict__ Ptk) {
    __shared__ float sA[8][256];
    __shared__ float ws[4][8][256];
    const int t = threadIdx.x, j = t & 255, q = t >> 8, b = blockIdx.x;
    const int i0 = b * 8;  // k-range [i0, i0+8)
    float acc[8];
    sA[2 * q][j]     = Pin[(i0 + 2 * q) * 256 + j];
    sA[2 * q + 1][j] = Pin[(i0 + 2 * q + 1) * 256 + j];
    __syncthreads();
    chain_core(sA, Bmat, j, q, acc);
#pragma unroll
    for (int r = 0; r < 8; ++r) ws[q][r][j] = acc[r];
    __syncthreads();
#pragma unroll
    for (int d = 0; d < 2; ++d) {
        const int r = 2 * q + d;
        const float v = ws[0][r][j] + ws[1][r][j] + ws[2][r][j] + ws[3][r][j];
        sA[r][j] += v;
    }
    __syncthreads();
    const int c = t >> 2, sub = t & 3;
    union { __bf16 h[2]; unsigned u; } pk;
    pk.h[0] = (__bf16)sA[sub * 2][c];
    pk.h[1] = (__bf16)sA[sub * 2 + 1][c];
    *(unsigned*)((void*)&Ptk[(size_t)(i0 >> 5) * 8192 + c * 32 + (i0 & 31) + sub * 2]) = pk.u;
}

// ---------------- big GEMM: y[65536][256] = x[65536][512] @ P ----------------
// Grid 2048 x 128 thr (2 waves, split-K). Block output 64x128; wave q accumulates
// k in [256q, 256q+256) = 8 tiles of 32. A: per-wave private LDS ring-2 xs[q][2][64][32]
// (32 KB), 8 gload_lds/tile. B: 8 pinned asm loads/tile, alternating reg sets. Steady
// vmcnt(16). End: barrier, LDS partial exchange with LITERAL acc indices (rule #20).
__global__ __launch_bounds__(128, 2) void nsm_gemm_xP(const float* __restrict__ x,
                                                      const __bf16* __restrict__ Ptk,
                                                      float* __restrict__ y) {
    __shared__ float xs[2][2][64][32];  // [wave][ring][row][k] 32 KB; reused for exchange
    const int tid = threadIdx.x;
    const int q = tid >> 6, lane = tid & 63;
    const int l15 = lane & 15, lhi = lane >> 4;

    const unsigned bid = blockIdx.x;
    const int xcd = bid & 7;
    const int w = bid >> 3;                    // 0..255
    const int stripe = xcd * 128 + (w >> 1);   // 0..1023
    const int nh = w & 1;
    const int m0 = stripe * 64;
    const int n0 = nh * 128;

    auto stageA = [&](int buf, int s) {
        const int kk = (q * 8 + s) * 32;
#pragma unroll
        for (int i = 0; i < 8; ++i) {
            const int r0 = i * 8;
            const int row = r0 + (lane >> 3);
            const int gch = (lane & 7) ^ (row & 7);
            GLOAD_LDS16(x + (size_t)(m0 + row) * IN + kk + gch * 4, &xs[q][buf][r0][0]);
        }
    };

    unsigned long long baddr = (unsigned long long)(const void*)Ptk +
                               (unsigned long long)(n0 * 64 + l15 * 64 + lhi * 16 + q * 131072);
    bf16x8 b0[8], b1[8];

#define LOADB(SET)                                                                        \
    do {                                                                                  \
        const unsigned long long baddr2 = baddr + 4096;                                   \
        _Pragma("unroll")                                                                 \
        for (int nt = 0; nt < 8; ++nt)                                                    \
            asm volatile("global_load_dwordx4 %0, %1, off offset:%2"                      \
                         : "=v"(SET[nt])                                                  \
                         : "v"(nt < 4 ? baddr : baddr2), "n"((nt & 3) * 1024));           \
        baddr += 16384;                                                                   \
    } while (0)

    f32x4 acc[4][8];
#pragma unroll
    for (int a = 0; a < 4; ++a)
#pragma unroll
        for (int c = 0; c < 8; ++c) acc[a][c] = (f32x4){0.f, 0.f, 0.f, 0.f};

    stageA(0, 0);
    LOADB(b0);
    stageA(1, 1);
    LOADB(b1);

#pragma unroll
    for (int s = 0; s < 8; ++s) {
        if (s < 7) {
            asm volatile("s_waitcnt vmcnt(16)" ::: "memory");  // tile s landed; s+1 in flight
        } else {
            asm volatile("s_waitcnt vmcnt(0)" ::: "memory");
        }
        __builtin_amdgcn_sched_barrier(0);

        const int buf = s & 1;  // static after full unroll
        f32x4 f0[4], f1[4];
#pragma unroll
        for (int mt = 0; mt < 4; ++mt) {
            const int row = mt * 16 + l15;
            const int c0 = (2 * lhi) ^ (row & 7);
            f0[mt] = *(const f32x4*)&xs[q][buf][row][c0 * 4];
            f1[mt] = *(const f32x4*)&xs[q][buf][row][(c0 ^ 1) * 4];
        }
        asm volatile("s_waitcnt lgkmcnt(0)" ::: "memory");  // frag reads in regs
        __builtin_amdgcn_sched_barrier(0);
        if (s < 6) stageA(buf, s + 2);  // ring-2 overwrite now safe

        bf16x8 af[4];
#pragma unroll
        for (int mt = 0; mt < 4; ++mt) {
            bf16x8 t;
            t[0] = (__bf16)f0[mt][0]; t[1] = (__bf16)f0[mt][1];
            t[2] = (__bf16)f0[mt][2]; t[3] = (__bf16)f0[mt][3];
            t[4] = (__bf16)f1[mt][0]; t[5] = (__bf16)f1[mt][1];
            t[6] = (__bf16)f1[mt][2]; t[7] = (__bf16)f1[mt][3];
            af[mt] = t;
        }

        if ((s & 1) == 0) {
#pragma unroll
            for (int mt = 0; mt < 4; ++mt)
#pragma unroll
                for (int nt = 0; nt < 8; ++nt)
                    acc[mt][nt] = __builtin_amdgcn_mfma_f32_16x16x32_bf16(af[mt], b0[nt], acc[mt][nt], 0, 0, 0);
            if (s < 6) LOADB(b0);
        } else {
#pragma unroll
            for (int mt = 0; mt < 4; ++mt)
#pragma unroll
                for (int nt = 0; nt < 8; ++nt)
                    acc[mt][nt] = __builtin_amdgcn_mfma_f32_16x16x32_bf16(af[mt], b1[nt], acc[mt][nt], 0, 0, 0);
            if (s < 6) LOADB(b1);
        }
    }
#undef LOADB

    // both waves done with their A-rings (vmcnt/lgkm drained in last iteration)
    __builtin_amdgcn_s_barrier();

    // split-K merge, ALL acc indices literal (rule #20). eb = dead A-ring, 2 halves of
    // [128 col][32 row] f32, XOR swizzle ((col&7)<<2).
    float* eb = &xs[0][0][0][0];

#define SEND(MT, ML, HALF)                                                                 \
    _Pragma("unroll")                                                                      \
    for (int nt = 0; nt < 8; ++nt) {                                                       \
        const int col = nt * 16 + l15;                                                     \
        const int rowp = (ML) * 16 + lhi * 4;                                              \
        *(f32x4*)&eb[((((HALF) * 128 + col) * 32 + rowp) ^ ((col & 7) << 2))] = acc[MT][nt]; \
    }
#define RECV(MT, ML, HALF)                                                                 \
    _Pragma("unroll")                                                                      \
    for (int nt = 0; nt < 8; ++nt) {                                                       \
        const int col = nt * 16 + l15;                                                     \
        const int rowp = (ML) * 16 + lhi * 4;                                              \
        const f32x4 v = *(const f32x4*)&eb[((((HALF) * 128 + col) * 32 + rowp) ^ ((col & 7) << 2))]; \
        acc[MT][nt] += v;                                                                  \
    }
#define STOREY(MT)                                                                         \
    _Pragma("unroll")                                                                      \
    for (int nt = 0; nt < 8; ++nt) {                                                       \
        const int col = n0 + nt * 16 + l15;                                                \
        const int row = m0 + (MT) * 16 + lhi * 4;                                          \
        _Pragma("unroll")                                                                  \
        for (int r = 0; r < 4; ++r) y[(size_t)(row + r) * OUT + col] = acc[MT][nt][r];     \
    }

    if (q == 0) {
        SEND(2, 0, 1)
        SEND(3, 1, 1)
        asm volatile("s_waitcnt lgkmcnt(0)" ::: "memory");
        __builtin_amdgcn_sched_barrier(0);
        __builtin_amdgcn_s_barrier();
        RECV(0, 0, 0)
        RECV(1, 1, 0)
        STOREY(0)
        STOREY(1)
    } else {
        SEND(0, 0, 0)
        SEND(1, 1, 0)
        asm volatile("s_waitcnt lgkmcnt(0)" ::: "memory");
        __builtin_amdgcn_sched_barrier(0);
        __builtin_amdgcn_s_barrier();
        RECV(2, 0, 1)
        RECV(3, 1, 1)
        STOREY(2)
        STOREY(3)
    }
#undef SEND
#undef RECV
#undef STOREY
}

extern "C" void kernel_launch(void* const* d_in, const int* in_sizes, int n_in,
                              void* d_out, int out_size, void* d_ws, size_t ws_size,
                              hipStream_t stream) {
    const float* x = (const float*)d_in[0];   // [65536][512]
    const float* W = (const float*)d_in[1];   // [256][512]
    const float* M = (const float*)d_in[2];   // [256][256]
    float* y = (float*)d_out;                 // [65536][256]

    char* ws = (char*)d_ws;
    float* Ta = (float*)(ws);                   // 256 KB
    float* Tb = (float*)(ws + (256 << 10));     // 256 KB
    float* Pa = (float*)(ws + (512 << 10));     // 512 KB
    float* Pb = (float*)(ws + (1024 << 10));    // 512 KB
    __bf16* Ptk = (__bf16*)(ws + (1536 << 10)); // 256 KB  bf16 k-major [16][256][32]

    // chain: P = W^T * prod_{i=0..3} (I + A^(2^i)), A = -M  (sum_{k=0}^{15} A^k)
    nsm_chain_step<<<96, 1024, 0, stream>>>(M, W, Ta, Pa, 1);   // Ta=A^2, Pa=P0=W^T(I+A)
    nsm_chain_step<<<96, 1024, 0, stream>>>(Ta, Pa, Tb, Pb, 0); // Tb=A^4, Pb=P1=P0(I+A^2)
    nsm_chain_step<<<96, 1024, 0, stream>>>(Tb, Pb, Ta, Pa, 0); // Ta=A^8, Pa=P2=P1(I+A^4)
    nsm_chain_last<<<64, 1024, 0, stream>>>(Ta, Pa, Ptk);       // Ptk = bf16((P2(I+A^8))^T)
    nsm_gemm_xP<<<2048, 128, 0, stream>>>(x, Ptk, y);           // y = x @ P
}

// Round 18
// 69.815 us; speedup vs baseline: 5.1824x; 1.0030x over previous
//
#include <hip/hip_runtime.h>
#include <hip/hip_bf16.h>

// y = x @ (W^T * S), S = sum_{k=0}^{100} (-M)^k ~= prod_{i=0}^{3} (I + A^(2^i)), A = -M.
// Chain: 4 k-parallel launches; last writes P k-major bf16 Ptk[kt][col][32] (verified R7-R17).
// GEMM: R12's barrier-free 1-wave pipeline, but the k-loop is a TRUE LOOP (7 iter x 2
// steps, unroll-disabled) instead of a ~20KB fully-unrolled body. Rationale: 8 designs
// all hit ~60us with <10% pipe utilization and ~1 instr/9cyc/CU issue -- consistent with
// I-cache-limited fetch of giant straight-line code + m141-style sched_barrier order-
// pinning. Loop body ~1.8KB; only load-bearing pins kept (vmcnt(16), lgkmcnt(0) +
// rule-#18 fence).

typedef float f32x4 __attribute__((ext_vector_type(4)));
typedef __bf16 bf16x8 __attribute__((ext_vector_type(8)));

#define IN 512
#define OUT 256
#define BATCH 65536

#define GLOAD_LDS16(gp, lp)                                                              \
    __builtin_amdgcn_global_load_lds((const __attribute__((address_space(1))) void*)(gp), \
                                     (__attribute__((address_space(3))) void*)(lp), 16, 0, 0)

// ---------------- chain: k-parallel small matmuls (verified rounds 1-17) ----------------
__device__ __forceinline__ void chain_core(const float (*sA)[256], const float* __restrict__ B,
                                           int j, int q, float acc[8]) {
#pragma unroll
    for (int r = 0; r < 8; ++r) acc[r] = 0.f;
    const int kbase = q * 64;
#pragma unroll
    for (int it = 0; it < 16; ++it) {
        const int k = kbase + it * 4;
        const float b0 = B[(k + 0) * 256 + j];
        const float b1 = B[(k + 1) * 256 + j];
        const float b2 = B[(k + 2) * 256 + j];
        const float b3 = B[(k + 3) * 256 + j];
#pragma unroll
        for (int r = 0; r < 8; ++r) {
            const f32x4 av = *(const f32x4*)&sA[r][k];
            acc[r] += av[0] * b0 + av[1] * b1 + av[2] * b2 + av[3] * b3;
        }
    }
}

__global__ __launch_bounds__(1024) void nsm_chain_step(const float* __restrict__ Bmat,
                                                       const float* __restrict__ Pin,
                                                       float* __restrict__ Tout,
                                                       float* __restrict__ Pout,
                                                       const int first) {
    __shared__ float sA[8][256];
    __shared__ float ws[4][8][256];
    const int t = threadIdx.x, j = t & 255, q = t >> 8, b = blockIdx.x;
    float acc[8];
    const bool isT = (b < 32);
    if (isT) {
        const int i0 = b * 8;
        sA[2 * q][j]     = Bmat[(i0 + 2 * q) * 256 + j];
        sA[2 * q + 1][j] = Bmat[(i0 + 2 * q + 1) * 256 + j];
    } else {
        const int i0 = (b - 32) * 8;
        if (first) {
            sA[2 * q][j]     = Pin[j * IN + i0 + 2 * q];
            sA[2 * q + 1][j] = Pin[j * IN + i0 + 2 * q + 1];
        } else {
            sA[2 * q][j]     = Pin[(i0 + 2 * q) * 256 + j];
            sA[2 * q + 1][j] = Pin[(i0 + 2 * q + 1) * 256 + j];
        }
    }
    __syncthreads();
    chain_core(sA, Bmat, j, q, acc);
#pragma unroll
    for (int r = 0; r < 8; ++r) ws[q][r][j] = acc[r];
    __syncthreads();
#pragma unroll
    for (int d = 0; d < 2; ++d) {
        const int r = 2 * q + d;
        const float v = ws[0][r][j] + ws[1][r][j] + ws[2][r][j] + ws[3][r][j];
        if (isT) {
            const int i0 = b * 8;
            Tout[(i0 + r) * 256 + j] = v;
        } else {
            const int i0 = (b - 32) * 8;
            Pout[(i0 + r) * 256 + j] = first ? (sA[r][j] - v) : (sA[r][j] + v);
        }
    }
}

// grid 64: P_final = Pin + Pin*Bmat, written K-MAJOR bf16: Ptk[kt][col][kk] (verified R7-R17).
__global__ __launch_bounds__(1024) void nsm_chain_last(const float* __restrict__ Bmat,
                                                       const float* __restrict__ Pin,
                                                       __bf16* __restrict__ Ptk) {
    __shared__ float sA[8][256];
    __shared__ float ws[4][8][256];
    const int t = threadIdx.x, j = t & 255, q = t >> 8, b = blockIdx.x;
    const int i0 = b * 8;  // k-range [i0, i0+8)
    float acc[8];
    sA[2 * q][j]     = Pin[(i0 + 2 * q) * 256 + j];
    sA[2 * q + 1][j] = Pin[(i0 + 2 * q + 1) * 256 + j];
    __syncthreads();
    chain_core(sA, Bmat, j, q, acc);
#pragma unroll
    for (int r = 0; r < 8; ++r) ws[q][r][j] = acc[r];
    __syncthreads();
#pragma unroll
    for (int d = 0; d < 2; ++d) {
        const int r = 2 * q + d;
        const float v = ws[0][r][j] + ws[1][r][j] + ws[2][r][j] + ws[3][r][j];
        sA[r][j] += v;
    }
    __syncthreads();
    const int c = t >> 2, sub = t & 3;
    union { __bf16 h[2]; unsigned u; } pk;
    pk.h[0] = (__bf16)sA[sub * 2][c];
    pk.h[1] = (__bf16)sA[sub * 2 + 1][c];
    *(unsigned*)((void*)&Ptk[(size_t)(i0 >> 5) * 8192 + c * 32 + (i0 & 31) + sub * 2]) = pk.u;
}

// ---------------- big GEMM: y[65536][256] = x[65536][512] @ P ----------------
// Grid 2048 x 64 thr (1 wave). bid -> (xcd, w): the two n-halves of an x-stripe are
// adjacent on the SAME XCD. Wave tile 64x128 (4mt x 8nt). A: LDS ring-2 xs[2][64][32]
// (16 KB), 8 gload_lds/tile. B: 8 pinned asm global_load_dwordx4/tile, sets b0/b1.
// Steady vmcnt(16); no s_barrier. K-LOOP IS A REAL LOOP: prologue (tiles 0,1), 7
// iterations x 2 steps (tiles 0..13, staging 2..15), epilogue steps 14,15.
__global__ __launch_bounds__(64, 2) void nsm_gemm_xP(const float* __restrict__ x,
                                                     const __bf16* __restrict__ Ptk,
                                                     float* __restrict__ y) {
    __shared__ float xs[2][64][32];  // 2 x 8 KB
    const int lane = threadIdx.x;
    const int l15 = lane & 15, lhi = lane >> 4;

    const unsigned bid = blockIdx.x;
    const int xcd = bid & 7;
    const int w = bid >> 3;                    // 0..255
    const int stripe = xcd * 128 + (w >> 1);   // 0..1023
    const int nh = w & 1;
    const int m0 = stripe * 64;
    const int n0 = nh * 128;

    // per-lane A source base pointers (8 gload_lds positions), advanced by kt*32 floats
    const float* abase[8];
#pragma unroll
    for (int i = 0; i < 8; ++i) {
        const int r0 = i * 8;
        const int row = r0 + (lane >> 3);
        const int gch = (lane & 7) ^ (row & 7);
        abase[i] = x + (size_t)(m0 + row) * IN + gch * 4;
    }

    auto stageA = [&](int buf, int kt) {
#pragma unroll
        for (int i = 0; i < 8; ++i) GLOAD_LDS16(abase[i] + kt * 32, &xs[buf][i * 8][0]);
    };

    unsigned long long baddr = (unsigned long long)(const void*)Ptk +
                               (unsigned long long)(n0 * 64 + l15 * 64 + lhi * 16);
    bf16x8 b0[8], b1[8];

#define LOADB(SET)                                                                        \
    do {                                                                                  \
        const unsigned long long baddr2 = baddr + 4096;                                   \
        _Pragma("unroll")                                                                 \
        for (int nt = 0; nt < 8; ++nt)                                                    \
            asm volatile("global_load_dwordx4 %0, %1, off offset:%2"                      \
                         : "=v"(SET[nt])                                                  \
                         : "v"(nt < 4 ? baddr : baddr2), "n"((nt & 3) * 1024));           \
        baddr += 16384;                                                                   \
    } while (0)

    f32x4 acc[4][8];
#pragma unroll
    for (int a = 0; a < 4; ++a)
#pragma unroll
        for (int c = 0; c < 8; ++c) acc[a][c] = (f32x4){0.f, 0.f, 0.f, 0.f};

    // frag read + cvt for one buffer (literal buf)
#define FRAGS(BUF, AF)                                                                    \
    do {                                                                                  \
        f32x4 f0_[4], f1_[4];                                                             \
        _Pragma("unroll")                                                                 \
        for (int mt = 0; mt < 4; ++mt) {                                                  \
            const int row = mt * 16 + l15;                                                \
            const int c0 = (2 * lhi) ^ (row & 7);                                         \
            f0_[mt] = *(const f32x4*)&xs[BUF][row][c0 * 4];                               \
            f1_[mt] = *(const f32x4*)&xs[BUF][row][(c0 ^ 1) * 4];                         \
        }                                                                                 \
        asm volatile("s_waitcnt lgkmcnt(0)" ::: "memory");                                \
        __builtin_amdgcn_sched_barrier(0); /* rule #18: no MFMA hoist above lgkm */       \
        _Pragma("unroll")                                                                 \
        for (int mt = 0; mt < 4; ++mt) {                                                  \
            bf16x8 t_;                                                                    \
            t_[0] = (__bf16)f0_[mt][0]; t_[1] = (__bf16)f0_[mt][1];                       \
            t_[2] = (__bf16)f0_[mt][2]; t_[3] = (__bf16)f0_[mt][3];                       \
            t_[4] = (__bf16)f1_[mt][0]; t_[5] = (__bf16)f1_[mt][1];                       \
            t_[6] = (__bf16)f1_[mt][2]; t_[7] = (__bf16)f1_[mt][3];                       \
            AF[mt] = t_;                                                                  \
        }                                                                                 \
    } while (0)

#define MFMAS(AF, BSET)                                                                   \
    _Pragma("unroll")                                                                     \
    for (int mt = 0; mt < 4; ++mt)                                                        \
        _Pragma("unroll")                                                                 \
        for (int nt = 0; nt < 8; ++nt)                                                    \
            acc[mt][nt] = __builtin_amdgcn_mfma_f32_16x16x32_bf16(AF[mt], BSET[nt], acc[mt][nt], 0, 0, 0);

    // prologue: tiles 0,1
    stageA(0, 0);
    LOADB(b0);
    stageA(1, 1);
    LOADB(b1);

    bf16x8 af[4];
#pragma clang loop unroll(disable)
    for (int it = 0; it < 7; ++it) {
        const int kt = it * 2;
        // even step: tile kt (buf 0, set b0); stage tile kt+2, load B tile kt+2
        asm volatile("s_waitcnt vmcnt(16)" ::: "memory");
        FRAGS(0, af);
        stageA(0, kt + 2);
        MFMAS(af, b0);
        LOADB(b0);
        // odd step: tile kt+1 (buf 1, set b1); stage tile kt+3, load B tile kt+3
        asm volatile("s_waitcnt vmcnt(16)" ::: "memory");
        FRAGS(1, af);
        stageA(1, kt + 3);
        MFMAS(af, b1);
        LOADB(b1);
    }
    // epilogue: tiles 14, 15 (no more staging)
    asm volatile("s_waitcnt vmcnt(16)" ::: "memory");
    FRAGS(0, af);
    MFMAS(af, b0);
    asm volatile("s_waitcnt vmcnt(0)" ::: "memory");
    FRAGS(1, af);
    MFMAS(af, b1);

#undef LOADB
#undef FRAGS
#undef MFMAS

#pragma unroll
    for (int mt = 0; mt < 4; ++mt) {
#pragma unroll
        for (int nt = 0; nt < 8; ++nt) {
            const int col = n0 + nt * 16 + l15;
            const int row = m0 + mt * 16 + lhi * 4;
#pragma unroll
            for (int r = 0; r < 4; ++r) y[(size_t)(row + r) * OUT + col] = acc[mt][nt][r];
        }
    }
}

extern "C" void kernel_launch(void* const* d_in, const int* in_sizes, int n_in,
                              void* d_out, int out_size, void* d_ws, size_t ws_size,
                              hipStream_t stream) {
    const float* x = (const float*)d_in[0];   // [65536][512]
    const float* W = (const float*)d_in[1];   // [256][512]
    const float* M = (const float*)d_in[2];   // [256][256]
    float* y = (float*)d_out;                 // [65536][256]

    char* ws = (char*)d_ws;
    float* Ta = (float*)(ws);                   // 256 KB
    float* Tb = (float*)(ws + (256 << 10));     // 256 KB
    float* Pa = (float*)(ws + (512 << 10));     // 512 KB
    float* Pb = (float*)(ws + (1024 << 10));    // 512 KB
    __bf16* Ptk = (__bf16*)(ws + (1536 << 10)); // 256 KB  bf16 k-major [16][256][32]

    // chain: P = W^T * prod_{i=0..3} (I + A^(2^i)), A = -M  (sum_{k=0}^{15} A^k)
    nsm_chain_step<<<96, 1024, 0, stream>>>(M, W, Ta, Pa, 1);   // Ta=A^2, Pa=P0=W^T(I+A)
    nsm_chain_step<<<96, 1024, 0, stream>>>(Ta, Pa, Tb, Pb, 0); // Tb=A^4, Pb=P1=P0(I+A^2)
    nsm_chain_step<<<96, 1024, 0, stream>>>(Tb, Pb, Ta, Pa, 0); // Ta=A^8, Pa=P2=P1(I+A^4)
    nsm_chain_last<<<64, 1024, 0, stream>>>(Ta, Pa, Ptk);       // Ptk = bf16((P2(I+A^8))^T)
    nsm_gemm_xP<<<2048, 64, 0, stream>>>(x, Ptk, y);            // y = x @ P
}